// Round 8
// baseline (375.247 us; speedup 1.0000x reference)
//
#include <hip/hip_runtime.h>

#define NNODES 40000
#define NEDGE  640000
#define NBUCK  625          // buckets per sign, 64 rows each
#define ECAP   1408         // per-bucket capacity (mean 1024, sd ~32)
#define QSZ16  1280000      // ushorts per quarter table (40000*32)
#define QSZU   640000       // uints per quarter table

typedef __attribute__((ext_vector_type(8))) short bfrag;
typedef __attribute__((ext_vector_type(4))) float facc;

union bfu { bfrag v; uint u[4]; };

__device__ inline ushort f2bf(float f) {
    uint u = __float_as_uint(f);
    return (ushort)((u + 0x7FFFu + ((u >> 16) & 1u)) >> 16);
}
__device__ inline float bf2f(ushort h) {
    return __uint_as_float(((uint)h) << 16);
}
__device__ inline float blo(uint u) { return __uint_as_float(u << 16); }
__device__ inline float bhi(uint u) { return __uint_as_float(u & 0xFFFF0000u); }

// ---------------- edge partition into 64-row buckets ----------------

__global__ __launch_bounds__(256) void partition_k(const int* __restrict__ pos_idx,
                                                   const float* __restrict__ pos_w,
                                                   const int* __restrict__ neg_idx,
                                                   const float* __restrict__ neg_w,
                                                   int* __restrict__ ecnt,
                                                   int2* __restrict__ edges) {
    __shared__ int lhist[2 * NBUCK];
    __shared__ int lbase[2 * NBUCK];
    long g0 = (long)blockIdx.x * 16384;
    for (int i = threadIdx.x; i < 2 * NBUCK; i += 256) lhist[i] = 0;
    __syncthreads();
    for (int i = 0; i < 64; ++i) {
        long g = g0 + i * 256 + threadIdx.x;
        if (g < 2 * NEDGE) {
            int sign = g >= NEDGE;
            int e = (int)(g - (long)sign * NEDGE);
            int row = sign ? neg_idx[e] : pos_idx[e];
            atomicAdd(&lhist[sign * NBUCK + (row >> 6)], 1);
        }
    }
    __syncthreads();
    for (int b = threadIdx.x; b < 2 * NBUCK; b += 256) {
        int c = lhist[b];
        lbase[b] = c ? atomicAdd(&ecnt[b], c) : 0;
        lhist[b] = 0;
    }
    __syncthreads();
    for (int i = 0; i < 64; ++i) {
        long g = g0 + i * 256 + threadIdx.x;
        if (g < 2 * NEDGE) {
            int sign = g >= NEDGE;
            int e = (int)(g - (long)sign * NEDGE);
            int row = sign ? neg_idx[e] : pos_idx[e];
            int col = sign ? neg_idx[NEDGE + e] : pos_idx[NEDGE + e];
            float wv = sign ? neg_w[e] : pos_w[e];
            int b = sign * NBUCK + (row >> 6);
            int off = lbase[b] + atomicAdd(&lhist[b], 1);
            if (off < ECAP)
                edges[(long)b * ECAP + off] =
                    make_int2((int)((uint)col | ((uint)(row & 63) << 16)), __float_as_int(wv));
        }
    }
}

// ---------------- bucket-local counting sort -> CSR (in-place) ----------------

__global__ __launch_bounds__(256) void bucket_csr_k(const int* __restrict__ ecnt,
                                                    int2* __restrict__ edges,
                                                    int2* __restrict__ rp2) {
    __shared__ int2 stage[ECAP];
    __shared__ int hist[64];
    __shared__ int base_[64];
    int b = blockIdx.x;
    int tid = threadIdx.x;
    int cnt = ecnt[b]; if (cnt > ECAP) cnt = ECAP;
    if (tid < 64) hist[tid] = 0;
    __syncthreads();
    long e0 = (long)b * ECAP;
    for (int i = tid; i < cnt; i += 256) {
        int2 e = edges[e0 + i];
        stage[i] = e;
        atomicAdd(&hist[((uint)e.x >> 16) & 63u], 1);
    }
    __syncthreads();
    if (tid < 64) {
        int v = hist[tid];
        int s = v;
#pragma unroll
        for (int off = 1; off < 64; off <<= 1) {
            int t = __shfl_up(s, off);
            if ((tid & 63) >= off) s += t;
        }
        int excl = s - v;
        base_[tid] = excl;
        int sign = b >= NBUCK;
        int r = (b - sign * NBUCK) * 64 + tid;
        rp2[sign * NNODES + r] = make_int2((int)(e0 + excl), (int)(e0 + excl + v));
        hist[tid] = 0;   // reuse as cursor
    }
    __syncthreads();
    for (int i = tid; i < cnt; i += 256) {
        int2 e = stage[i];
        int rl = ((uint)e.x >> 16) & 63u;
        int pos = base_[rl] + atomicAdd(&hist[rl], 1);
        edges[e0 + pos] = make_int2(e.x & 0xFFFF, e.y);
    }
}

// ---------------- pack all W into MFMA B-fragment order ----------------

__global__ __launch_bounds__(256) void pack_all_k(const float* __restrict__ Wo,
                                                  const float* __restrict__ Wp,
                                                  const float* __restrict__ Wn,
                                                  const float* __restrict__ Wm,
                                                  ushort* __restrict__ out) {
    int idx = blockIdx.x * 256 + threadIdx.x;      // 0..98303
    const float* W;
    ushort* dst;
    int local;
    if (idx < 49152) {
        int m = idx >> 14;
        local = idx & 16383;
        W = (m == 0) ? Wo : (m == 1) ? Wp : Wn;
        dst = out + m * 16384;
    } else {
        local = idx - 49152;
        W = Wm;
        dst = out + 49152;
    }
    int j = local & 7, l = (local >> 3) & 63, t = (local >> 9) & 7, ks = local >> 12;
    int k = ks * 32 + (l >> 4) * 8 + j;
    int c = (l & 15) + 16 * t;
    dst[local] = f2bf(W[k * 128 + c]);
}

// ---------------- fused triple MFMA GEMM: x(f32) @ {W_org,W_pos,W_neg} ----------------
// outputs quarter-blocked bf16; fused per-channel stats for org.

__global__ __launch_bounds__(256) void mfma_gemm3_k(const float* __restrict__ x,
                                                    const ushort* __restrict__ B0,
                                                    const ushort* __restrict__ B1,
                                                    const ushort* __restrict__ B2,
                                                    ushort* __restrict__ O0,
                                                    ushort* __restrict__ O1,
                                                    ushort* __restrict__ O2,
                                                    float* __restrict__ sums,
                                                    float* __restrict__ sumsq) {
    __shared__ float cs[128], cq[128];
    int tid = threadIdx.x;
    int lane = tid & 63, wave = tid >> 6;
    if (tid < 128) { cs[tid] = 0.f; cq[tid] = 0.f; }
    __syncthreads();
    long rbase = (long)blockIdx.x * 64 + wave * 16;
    int r = lane & 15, kg = lane >> 4;
    const float* xr = x + (rbase + r) * 128 + kg * 8;
    bfrag a[4];
#pragma unroll
    for (int ks = 0; ks < 4; ++ks) {
        float4 lo = *(const float4*)(xr + ks * 32);
        float4 hi = *(const float4*)(xr + ks * 32 + 4);
        bfu t;
        t.u[0] = (uint)f2bf(lo.x) | ((uint)f2bf(lo.y) << 16);
        t.u[1] = (uint)f2bf(lo.z) | ((uint)f2bf(lo.w) << 16);
        t.u[2] = (uint)f2bf(hi.x) | ((uint)f2bf(hi.y) << 16);
        t.u[3] = (uint)f2bf(hi.z) | ((uint)f2bf(hi.w) << 16);
        a[ks] = t.v;
    }
    const ushort* Bs[3] = {B0, B1, B2};
    ushort* Os[3] = {O0, O1, O2};
    long orow = rbase + kg * 4;
#pragma unroll
    for (int m = 0; m < 3; ++m) {
        const bfrag* Bq = (const bfrag*)Bs[m] + lane;
        facc acc[8];
#pragma unroll
        for (int t = 0; t < 8; ++t) acc[t] = (facc){0.f, 0.f, 0.f, 0.f};
#pragma unroll
        for (int ks = 0; ks < 4; ++ks)
#pragma unroll
            for (int t = 0; t < 8; ++t)
                acc[t] = __builtin_amdgcn_mfma_f32_16x16x32_bf16(a[ks], Bq[(ks * 8 + t) * 64], acc[t], 0, 0, 0);
        ushort* O = Os[m];
#pragma unroll
        for (int t = 0; t < 8; ++t) {
            float s_ = 0.f, q_ = 0.f;
            // channel c = 16t + r -> blocked: q = t>>1, cc = (t&1)*16 + r
            long qb = (long)(t >> 1) * QSZ16 + (t & 1) * 16 + r;
#pragma unroll
            for (int j = 0; j < 4; ++j) {
                ushort bv = f2bf(acc[t][j]);
                O[qb + (orow + j) * 32] = bv;
                if (m == 0) {
                    float fv = bf2f(bv);
                    s_ += fv;
                    q_ = fmaf(fv, fv, q_);
                }
            }
            if (m == 0) {
                atomicAdd(&cs[16 * t + r], s_);
                atomicAdd(&cq[16 * t + r], q_);
            }
        }
    }
    __syncthreads();
    if (tid < 128) {
        atomicAdd(&sums[tid], cs[tid]);
        atomicAdd(&sumsq[tid], cq[tid]);
    }
}

// ---------------- quarter-blocked SpMM, XCD-pinned, nt-streams, dual-row ILP ----
// grp = blockIdx.x & 7 pins each (sign,quarter) to one XCD (2.56 MB table in L2).
// Streaming data (edges, rp2, prev) uses non-temporal loads so it doesn't evict
// the gather table. Two rows per thread processed with interleaved accumulator
// chains for 2x memory-level parallelism.

template<int PHASE>
__global__ __launch_bounds__(256) void spmmq_k(const int2* __restrict__ rp2,
                                               const int2* __restrict__ edges,
                                               const uint* __restrict__ p_in,
                                               const uint* __restrict__ n_in,
                                               const uint* __restrict__ p_prev,
                                               const uint* __restrict__ n_prev,
                                               uint* __restrict__ p_out,
                                               uint* __restrict__ n_out) {
    int grp = blockIdx.x & 7;
    int rg  = blockIdx.x >> 3;
    int sign = grp >> 2, q = grp & 3;
    int tid = threadIdx.x;
    int w = tid >> 6, lane = tid & 63;
    int u = lane & 7, g = lane >> 3;
    const uint2* in = (const uint2*)((sign ? n_in : p_in) + q * QSZU);
    uint2* out = (uint2*)((sign ? n_out : p_out) + q * QSZU);
    const uint2* prev = (PHASE == 2) ? (const uint2*)((sign ? n_prev : p_prev) + q * QSZU) : nullptr;
    const int2* rp = rp2 + sign * NNODES;
    int r = rg * 8 + w * 2;
    long long sv0 = __builtin_nontemporal_load((const long long*)(rp + r));
    long long sv1 = __builtin_nontemporal_load((const long long*)(rp + r + 1));
    int e0 = (int)sv0, e0n = (int)(sv0 >> 32);
    int e1 = (int)sv1, e1n = (int)(sv1 >> 32);
    float a0 = 0.f, b0 = 0.f, c0 = 0.f, d0 = 0.f;
    float a1 = 0.f, b1 = 0.f, c1 = 0.f, d1 = 0.f;
    // fused main loop: both rows advance together -> 2 gathers in flight
    while (e0 + 8 <= e0n && e1 + 8 <= e1n) {
        long long ea = __builtin_nontemporal_load((const long long*)(edges + e0 + g));
        long long eb = __builtin_nontemporal_load((const long long*)(edges + e1 + g));
        uint2 ga = in[(uint)(ea & 0xFFFF) * 8 + u];
        uint2 gb = in[(uint)(eb & 0xFFFF) * 8 + u];
        float wa = __int_as_float((int)(ea >> 32));
        float wb = __int_as_float((int)(eb >> 32));
        a0 = fmaf(wa, blo(ga.x), a0); b0 = fmaf(wa, bhi(ga.x), b0);
        c0 = fmaf(wa, blo(ga.y), c0); d0 = fmaf(wa, bhi(ga.y), d0);
        a1 = fmaf(wb, blo(gb.x), a1); b1 = fmaf(wb, bhi(gb.x), b1);
        c1 = fmaf(wb, blo(gb.y), c1); d1 = fmaf(wb, bhi(gb.y), d1);
        e0 += 8; e1 += 8;
    }
    while (e0 < e0n) {
        int kk = e0 + g;
        long long ea = (kk < e0n) ? __builtin_nontemporal_load((const long long*)(edges + kk))
                                  : 0LL;
        uint2 ga = in[(uint)(ea & 0xFFFF) * 8 + u];
        float wa = __int_as_float((int)(ea >> 32));
        a0 = fmaf(wa, blo(ga.x), a0); b0 = fmaf(wa, bhi(ga.x), b0);
        c0 = fmaf(wa, blo(ga.y), c0); d0 = fmaf(wa, bhi(ga.y), d0);
        e0 += 8;
    }
    while (e1 < e1n) {
        int kk = e1 + g;
        long long eb = (kk < e1n) ? __builtin_nontemporal_load((const long long*)(edges + kk))
                                  : 0LL;
        uint2 gb = in[(uint)(eb & 0xFFFF) * 8 + u];
        float wb = __int_as_float((int)(eb >> 32));
        a1 = fmaf(wb, blo(gb.x), a1); b1 = fmaf(wb, bhi(gb.x), b1);
        c1 = fmaf(wb, blo(gb.y), c1); d1 = fmaf(wb, bhi(gb.y), d1);
        e1 += 8;
    }
#pragma unroll
    for (int m = 8; m <= 32; m <<= 1) {
        a0 += __shfl_xor(a0, m); b0 += __shfl_xor(b0, m);
        c0 += __shfl_xor(c0, m); d0 += __shfl_xor(d0, m);
        a1 += __shfl_xor(a1, m); b1 += __shfl_xor(b1, m);
        c1 += __shfl_xor(c1, m); d1 += __shfl_xor(d1, m);
    }
    if (g < 2) {
        int rr = r + g;
        float sx = g ? a1 : a0, sy = g ? b1 : b0;
        float sz = g ? c1 : c0, sw = g ? d1 : d0;
        uint2 res;
        if (PHASE == 1) {
            res.x = (uint)f2bf(2.f * sx) | ((uint)f2bf(2.f * sy) << 16);
            res.y = (uint)f2bf(2.f * sz) | ((uint)f2bf(2.f * sw) << 16);
        } else {
            long long pv = __builtin_nontemporal_load((const long long*)(prev + rr * 8 + u));
            uint pux = (uint)pv, puy = (uint)(pv >> 32);
            float rx = fmaf(1.875f, sx, -1.6875f * blo(pux));
            float ry = fmaf(1.875f, sy, -1.6875f * bhi(pux));
            float rz = fmaf(1.875f, sz, -1.6875f * blo(puy));
            float rw = fmaf(1.875f, sw, -1.6875f * bhi(puy));
            res.x = (uint)f2bf(rx) | ((uint)f2bf(ry) << 16);
            res.y = (uint)f2bf(rz) | ((uint)f2bf(rw) << 16);
        }
        out[rr * 8 + u] = res;
    }
}

// ---------------- batch stats for pos & neg (quarter-blocked bf16 input) ----------------

__global__ __launch_bounds__(256) void stats2_k(const ushort* __restrict__ pos,
                                                const ushort* __restrict__ neg,
                                                float* __restrict__ sums,
                                                float* __restrict__ sumsq) {
    int b = blockIdx.x;            // 626 blocks
    int sign = b >= 313;
    int blk = b - sign * 313;
    const ushort* buf = sign ? neg : pos;
    int c = threadIdx.x & 127, half = threadIdx.x >> 7;
    int qq = c >> 5, cc = c & 31;
    const ushort* base = buf + (long)qq * QSZ16 + cc;
    int r0 = blk * 128;
    int rend = r0 + 128; if (rend > NNODES) rend = NNODES;
    float s = 0.f, s2 = 0.f;
    for (int r = r0 + half; r < rend; r += 2) {
        float v = bf2f(base[r * 32]);
        s += v;
        s2 = fmaf(v, v, s2);
    }
    __shared__ float sh[256], sh2[256];
    sh[threadIdx.x] = s; sh2[threadIdx.x] = s2;
    __syncthreads();
    if (threadIdx.x < 128) {
        int sb = 128 + sign * 128;
        atomicAdd(&sums[sb + c],  sh[c]  + sh[c + 128]);
        atomicAdd(&sumsq[sb + c], sh2[c] + sh2[c + 128]);
    }
}

__global__ void bnfin_k(const float* __restrict__ sum, const float* __restrict__ sumsq,
                        const float* __restrict__ g0, const float* __restrict__ be0,
                        const float* __restrict__ g1, const float* __restrict__ be1,
                        const float* __restrict__ g2, const float* __restrict__ be2,
                        float* __restrict__ bn) {
    int i = threadIdx.x;
    if (i >= 384) return;
    int s = i >> 7, c = i & 127;
    float mean = sum[i] * (1.f / NNODES);
    float var  = sumsq[i] * (1.f / NNODES) - mean * mean;
    const float* g = (s == 0) ? g0 : (s == 1) ? g1 : g2;
    const float* b = (s == 0) ? be0 : (s == 1) ? be1 : be2;
    float sc = g[c] * rsqrtf(var + 1e-5f);
    bn[s * 256 + c]       = sc;
    bn[s * 256 + 128 + c] = b[c] - mean * sc;
}

// ---------------- final MFMA GEMM K=384 with fused BN+PReLU+concat + row-norm ----------------

__global__ __launch_bounds__(256) void mfma_gemm_mlp_k(const ushort* __restrict__ org,
                                                       const ushort* __restrict__ pos,
                                                       const ushort* __restrict__ neg,
                                                       const float* __restrict__ bn,
                                                       const float* __restrict__ prelu_w,
                                                       const ushort* __restrict__ Bp,
                                                       float* __restrict__ Out) {
    int lane = threadIdx.x & 63, wave = threadIdx.x >> 6;
    long rbase = (long)blockIdx.x * 64 + wave * 16;
    int r = lane & 15, kg = lane >> 4;
    float pw = prelu_w[0];
    facc acc[8];
#pragma unroll
    for (int t = 0; t < 8; ++t) acc[t] = (facc){0.f, 0.f, 0.f, 0.f};
    const bfrag* Bq = (const bfrag*)Bp + lane;
#pragma unroll
    for (int ks = 0; ks < 12; ++ks) {
        int c = ks * 32 + kg * 8;          // concat column of first elem
        int s = c >> 7;
        int off = c & 127;
        const ushort* src = (s == 0) ? org : (s == 1) ? pos : neg;
        const uint* srcu = (const uint*)src;
        uint4 u = *(const uint4*)(srcu + (long)(off >> 5) * QSZU + (rbase + r) * 16 + ((off & 31) >> 1));
        float4 sc_lo = *(const float4*)(bn + s * 256 + off);
        float4 sc_hi = *(const float4*)(bn + s * 256 + off + 4);
        float4 sh_lo = *(const float4*)(bn + s * 256 + 128 + off);
        float4 sh_hi = *(const float4*)(bn + s * 256 + 128 + off + 4);
        uint uu[4] = {u.x, u.y, u.z, u.w};
        float scv[8] = {sc_lo.x, sc_lo.y, sc_lo.z, sc_lo.w, sc_hi.x, sc_hi.y, sc_hi.z, sc_hi.w};
        float shv[8] = {sh_lo.x, sh_lo.y, sh_lo.z, sh_lo.w, sh_hi.x, sh_hi.y, sh_hi.z, sh_hi.w};
        bfu av;
#pragma unroll
        for (int k = 0; k < 4; ++k) {
            float vx = __uint_as_float(uu[k] << 16);
            float vy = __uint_as_float(uu[k] & 0xFFFF0000u);
            float ox = fmaf(vx, scv[2 * k],     shv[2 * k]);     ox = (ox >= 0.f) ? ox : pw * ox;
            float oy = fmaf(vy, scv[2 * k + 1], shv[2 * k + 1]); oy = (oy >= 0.f) ? oy : pw * oy;
            av.u[k] = (uint)f2bf(ox) | ((uint)f2bf(oy) << 16);
        }
#pragma unroll
        for (int t = 0; t < 8; ++t)
            acc[t] = __builtin_amdgcn_mfma_f32_16x16x32_bf16(av.v, Bq[(ks * 8 + t) * 64], acc[t], 0, 0, 0);
    }
    long orow = rbase + kg * 4;
#pragma unroll
    for (int j = 0; j < 4; ++j) {
        float ss = 0.f;
#pragma unroll
        for (int t = 0; t < 8; ++t) ss = fmaf(acc[t][j], acc[t][j], ss);
        ss += __shfl_xor(ss, 1);
        ss += __shfl_xor(ss, 2);
        ss += __shfl_xor(ss, 4);
        ss += __shfl_xor(ss, 8);
        float inv = 1.f / fmaxf(sqrtf(ss), 1e-12f);
#pragma unroll
        for (int t = 0; t < 8; ++t)
            Out[(orow + j) * 128 + 16 * t + r] = acc[t][j] * inv;
    }
}

// ---------------- launch ----------------

extern "C" void kernel_launch(void* const* d_in, const int* in_sizes, int n_in,
                              void* d_out, int out_size, void* d_ws, size_t ws_size,
                              hipStream_t stream) {
    const float* x       = (const float*)d_in[0];
    const int*   pos_idx = (const int*)d_in[1];
    const float* pos_w   = (const float*)d_in[2];
    const int*   neg_idx = (const int*)d_in[3];
    const float* neg_w   = (const float*)d_in[4];
    const float* W_org   = (const float*)d_in[5];
    const float* W_pos   = (const float*)d_in[6];
    const float* W_neg   = (const float*)d_in[7];
    const float* g_org   = (const float*)d_in[8];
    const float* b_org   = (const float*)d_in[9];
    const float* g_pos   = (const float*)d_in[10];
    const float* b_pos   = (const float*)d_in[11];
    const float* g_neg   = (const float*)d_in[12];
    const float* b_neg   = (const float*)d_in[13];
    const float* prelu_w = (const float*)d_in[14];
    const float* W_mlp   = (const float*)d_in[15];
    float* out = (float*)d_out;

    char* ws = (char*)d_ws;
    const size_t FB = (size_t)NNODES * 128 * 2;        // 10,240,000 B per feature buffer
    ushort* org0b = (ushort*)(ws);
    ushort* p0b   = (ushort*)(ws + FB);
    ushort* n0b   = (ushort*)(ws + 2 * FB);
    int2* edges   = (int2*)(ws + 3 * FB);              // 14,080,000 B
    char* small   = ws + 3 * FB + 14080000;
    int* ecnt     = (int*)small;                       // 5000 -> pad 5120
    float* sums   = (float*)(small + 5120);            // 1536
    float* sumsq  = (float*)(small + 5120 + 1536);     // 1536 (memset 0..8192)
    float* bn     = (float*)(small + 8192);            // 3072
    int2* rp2     = (int2*)(small + 8192 + 3072);      // 640,000
    ushort* Wb    = (ushort*)(small + 8192 + 3072 + 640000);   // 196,608 B
    uint* t1_pos  = (uint*)d_out;                      // blocked bf16 scratch halves of d_out
    uint* t1_neg  = (uint*)d_out + 4 * QSZU;

    hipMemsetAsync(small, 0, 8192, stream);

    partition_k<<<79, 256, 0, stream>>>(pos_idx, pos_w, neg_idx, neg_w, ecnt, edges);
    bucket_csr_k<<<2 * NBUCK, 256, 0, stream>>>(ecnt, edges, rp2);
    pack_all_k<<<384, 256, 0, stream>>>(W_org, W_pos, W_neg, W_mlp, Wb);

    mfma_gemm3_k<<<625, 256, 0, stream>>>(x, Wb, Wb + 16384, Wb + 32768,
                                          org0b, p0b, n0b, sums, sumsq);

    // Jacobi (a=b=1, K=3): x1 = 2*A@x0 ; x2 = 1.875*A@x1 - 1.6875*x0
    spmmq_k<1><<<40000, 256, 0, stream>>>(rp2, edges,
        (const uint*)p0b, (const uint*)n0b, nullptr, nullptr, t1_pos, t1_neg);
    spmmq_k<2><<<40000, 256, 0, stream>>>(rp2, edges,
        t1_pos, t1_neg, (const uint*)p0b, (const uint*)n0b, (uint*)p0b, (uint*)n0b);

    stats2_k<<<626, 256, 0, stream>>>(p0b, n0b, sums, sumsq);
    bnfin_k<<<1, 384, 0, stream>>>(sums, sumsq, g_org, b_org, g_pos, b_pos, g_neg, b_neg, bn);
    mfma_gemm_mlp_k<<<625, 256, 0, stream>>>(org0b, p0b, n0b, bn, prelu_w, Wb + 49152, out);

    (void)in_sizes; (void)n_in; (void)out_size; (void)ws_size;
}

// Round 9
// 323.256 us; speedup vs baseline: 1.1608x; 1.1608x over previous
//
#include <hip/hip_runtime.h>

#define NNODES 40000
#define NEDGE  640000
#define NBUCK  625          // buckets per sign, 64 rows each
#define ECAP   1408         // per-bucket capacity (mean 1024, sd ~32)
#define QSZ16  1280000      // ushorts per quarter table (40000*32)
#define QSZU   640000       // uints per quarter table

typedef __attribute__((ext_vector_type(8))) short bfrag;
typedef __attribute__((ext_vector_type(4))) float facc;

union bfu { bfrag v; uint u[4]; };

__device__ inline ushort f2bf(float f) {
    uint u = __float_as_uint(f);
    return (ushort)((u + 0x7FFFu + ((u >> 16) & 1u)) >> 16);
}
__device__ inline float bf2f(ushort h) {
    return __uint_as_float(((uint)h) << 16);
}
__device__ inline float blo(uint u) { return __uint_as_float(u << 16); }
__device__ inline float bhi(uint u) { return __uint_as_float(u & 0xFFFF0000u); }

// ---------------- edge partition into 64-row buckets ----------------

__global__ __launch_bounds__(256) void partition_k(const int* __restrict__ pos_idx,
                                                   const float* __restrict__ pos_w,
                                                   const int* __restrict__ neg_idx,
                                                   const float* __restrict__ neg_w,
                                                   int* __restrict__ ecnt,
                                                   int2* __restrict__ edges) {
    __shared__ int lhist[2 * NBUCK];
    __shared__ int lbase[2 * NBUCK];
    long g0 = (long)blockIdx.x * 16384;
    for (int i = threadIdx.x; i < 2 * NBUCK; i += 256) lhist[i] = 0;
    __syncthreads();
    for (int i = 0; i < 64; ++i) {
        long g = g0 + i * 256 + threadIdx.x;
        if (g < 2 * NEDGE) {
            int sign = g >= NEDGE;
            int e = (int)(g - (long)sign * NEDGE);
            int row = sign ? neg_idx[e] : pos_idx[e];
            atomicAdd(&lhist[sign * NBUCK + (row >> 6)], 1);
        }
    }
    __syncthreads();
    for (int b = threadIdx.x; b < 2 * NBUCK; b += 256) {
        int c = lhist[b];
        lbase[b] = c ? atomicAdd(&ecnt[b], c) : 0;
        lhist[b] = 0;
    }
    __syncthreads();
    for (int i = 0; i < 64; ++i) {
        long g = g0 + i * 256 + threadIdx.x;
        if (g < 2 * NEDGE) {
            int sign = g >= NEDGE;
            int e = (int)(g - (long)sign * NEDGE);
            int row = sign ? neg_idx[e] : pos_idx[e];
            int col = sign ? neg_idx[NEDGE + e] : pos_idx[NEDGE + e];
            float wv = sign ? neg_w[e] : pos_w[e];
            int b = sign * NBUCK + (row >> 6);
            int off = lbase[b] + atomicAdd(&lhist[b], 1);
            if (off < ECAP)
                edges[(long)b * ECAP + off] =
                    make_int2((int)((uint)col | ((uint)(row & 63) << 16)), __float_as_int(wv));
        }
    }
}

// ---------------- bucket-local counting sort -> compressed CSR ----------------
// block = one bucket; stage edges in LDS, 64-bin hist+scan, emit 4-byte edges
// (col | bf16weight<<16) sorted by row; rp2[row] = (start, end) in edge units.

__global__ __launch_bounds__(256) void bucket_csr_k(const int* __restrict__ ecnt,
                                                    const int2* __restrict__ edges,
                                                    uint* __restrict__ ecomp,
                                                    int2* __restrict__ rp2) {
    __shared__ int2 stage[ECAP];
    __shared__ int hist[64];
    __shared__ int base_[64];
    int b = blockIdx.x;
    int tid = threadIdx.x;
    int cnt = ecnt[b]; if (cnt > ECAP) cnt = ECAP;
    if (tid < 64) hist[tid] = 0;
    __syncthreads();
    long e0 = (long)b * ECAP;
    for (int i = tid; i < cnt; i += 256) {
        int2 e = edges[e0 + i];
        stage[i] = e;
        atomicAdd(&hist[((uint)e.x >> 16) & 63u], 1);
    }
    __syncthreads();
    if (tid < 64) {
        int v = hist[tid];
        int s = v;
#pragma unroll
        for (int off = 1; off < 64; off <<= 1) {
            int t = __shfl_up(s, off);
            if ((tid & 63) >= off) s += t;
        }
        int excl = s - v;
        base_[tid] = excl;
        int sign = b >= NBUCK;
        int r = (b - sign * NBUCK) * 64 + tid;
        rp2[sign * NNODES + r] = make_int2((int)(e0 + excl), (int)(e0 + excl + v));
        hist[tid] = 0;   // reuse as cursor
    }
    __syncthreads();
    for (int i = tid; i < cnt; i += 256) {
        int2 e = stage[i];
        int rl = ((uint)e.x >> 16) & 63u;
        int pos = base_[rl] + atomicAdd(&hist[rl], 1);
        ecomp[e0 + pos] = ((uint)e.x & 0xFFFFu) |
                          ((uint)f2bf(__int_as_float(e.y)) << 16);
    }
}

// ---------------- pack all W into MFMA B-fragment order ----------------

__global__ __launch_bounds__(256) void pack_all_k(const float* __restrict__ Wo,
                                                  const float* __restrict__ Wp,
                                                  const float* __restrict__ Wn,
                                                  const float* __restrict__ Wm,
                                                  ushort* __restrict__ out) {
    int idx = blockIdx.x * 256 + threadIdx.x;      // 0..98303
    const float* W;
    ushort* dst;
    int local;
    if (idx < 49152) {
        int m = idx >> 14;
        local = idx & 16383;
        W = (m == 0) ? Wo : (m == 1) ? Wp : Wn;
        dst = out + m * 16384;
    } else {
        local = idx - 49152;
        W = Wm;
        dst = out + 49152;
    }
    int j = local & 7, l = (local >> 3) & 63, t = (local >> 9) & 7, ks = local >> 12;
    int k = ks * 32 + (l >> 4) * 8 + j;
    int c = (l & 15) + 16 * t;
    dst[local] = f2bf(W[k * 128 + c]);
}

// ---------------- fused triple MFMA GEMM: x(f32) @ {W_org,W_pos,W_neg} ----------------
// outputs quarter-blocked bf16; fused per-channel stats for org.

__global__ __launch_bounds__(256) void mfma_gemm3_k(const float* __restrict__ x,
                                                    const ushort* __restrict__ B0,
                                                    const ushort* __restrict__ B1,
                                                    const ushort* __restrict__ B2,
                                                    ushort* __restrict__ O0,
                                                    ushort* __restrict__ O1,
                                                    ushort* __restrict__ O2,
                                                    float* __restrict__ sums,
                                                    float* __restrict__ sumsq) {
    __shared__ float cs[128], cq[128];
    int tid = threadIdx.x;
    int lane = tid & 63, wave = tid >> 6;
    if (tid < 128) { cs[tid] = 0.f; cq[tid] = 0.f; }
    __syncthreads();
    long rbase = (long)blockIdx.x * 64 + wave * 16;
    int r = lane & 15, kg = lane >> 4;
    const float* xr = x + (rbase + r) * 128 + kg * 8;
    bfrag a[4];
#pragma unroll
    for (int ks = 0; ks < 4; ++ks) {
        float4 lo = *(const float4*)(xr + ks * 32);
        float4 hi = *(const float4*)(xr + ks * 32 + 4);
        bfu t;
        t.u[0] = (uint)f2bf(lo.x) | ((uint)f2bf(lo.y) << 16);
        t.u[1] = (uint)f2bf(lo.z) | ((uint)f2bf(lo.w) << 16);
        t.u[2] = (uint)f2bf(hi.x) | ((uint)f2bf(hi.y) << 16);
        t.u[3] = (uint)f2bf(hi.z) | ((uint)f2bf(hi.w) << 16);
        a[ks] = t.v;
    }
    const ushort* Bs[3] = {B0, B1, B2};
    ushort* Os[3] = {O0, O1, O2};
    long orow = rbase + kg * 4;
#pragma unroll
    for (int m = 0; m < 3; ++m) {
        const bfrag* Bq = (const bfrag*)Bs[m] + lane;
        facc acc[8];
#pragma unroll
        for (int t = 0; t < 8; ++t) acc[t] = (facc){0.f, 0.f, 0.f, 0.f};
#pragma unroll
        for (int ks = 0; ks < 4; ++ks)
#pragma unroll
            for (int t = 0; t < 8; ++t)
                acc[t] = __builtin_amdgcn_mfma_f32_16x16x32_bf16(a[ks], Bq[(ks * 8 + t) * 64], acc[t], 0, 0, 0);
        ushort* O = Os[m];
#pragma unroll
        for (int t = 0; t < 8; ++t) {
            float s_ = 0.f, q_ = 0.f;
            // channel c = 16t + r -> blocked: q = t>>1, cc = (t&1)*16 + r
            long qb = (long)(t >> 1) * QSZ16 + (t & 1) * 16 + r;
#pragma unroll
            for (int j = 0; j < 4; ++j) {
                ushort bv = f2bf(acc[t][j]);
                O[qb + (orow + j) * 32] = bv;
                if (m == 0) {
                    float fv = bf2f(bv);
                    s_ += fv;
                    q_ = fmaf(fv, fv, q_);
                }
            }
            if (m == 0) {
                atomicAdd(&cs[16 * t + r], s_);
                atomicAdd(&cq[16 * t + r], q_);
            }
        }
    }
    __syncthreads();
    if (tid < 128) {
        atomicAdd(&sums[tid], cs[tid]);
        atomicAdd(&sumsq[tid], cq[tid]);
    }
}

// ---------------- quarter-blocked SpMM, XCD-pinned, compressed edges ----------------
// grp = blockIdx.x & 7 pins each (sign,quarter) group to one XCD so its 2.56 MB
// table stays L2-resident. Edge = uint (col | bf16w<<16): 4 B/edge stream.
// block = 4 waves x 2 rows; wave: 8-lane group g handles edge e+g (uint2 = 4ch).

template<int PHASE>
__global__ __launch_bounds__(256) void spmmq_k(const int2* __restrict__ rp2,
                                               const uint* __restrict__ ec,
                                               const uint* __restrict__ p_in,
                                               const uint* __restrict__ n_in,
                                               const uint* __restrict__ p_prev,
                                               const uint* __restrict__ n_prev,
                                               uint* __restrict__ p_out,
                                               uint* __restrict__ n_out) {
    int grp = blockIdx.x & 7;
    int rg  = blockIdx.x >> 3;
    int sign = grp >> 2, q = grp & 3;
    int tid = threadIdx.x;
    int w = tid >> 6, lane = tid & 63;
    int u = lane & 7, g = lane >> 3;
    const uint2* in = (const uint2*)((sign ? n_in : p_in) + q * QSZU);
    uint2* out = (uint2*)((sign ? n_out : p_out) + q * QSZU);
    const uint2* prev = (PHASE == 2) ? (const uint2*)((sign ? n_prev : p_prev) + q * QSZU) : nullptr;
    const int2* rp = rp2 + sign * NNODES;
#pragma unroll
    for (int rr = 0; rr < 2; ++rr) {
        int r = rg * 8 + w * 2 + rr;
        int2 se = rp[r];
        float ax = 0.f, ay = 0.f, az = 0.f, aw = 0.f;
        float bx = 0.f, by = 0.f, bz = 0.f, bw = 0.f;
        int e = se.x, e1 = se.y;
        for (; e + 16 <= e1; e += 16) {
            uint ea = ec[e + g];
            uint eb = ec[e + 8 + g];
            uint2 ga = in[(ea & 0xFFFFu) * 8 + u];
            uint2 gb = in[(eb & 0xFFFFu) * 8 + u];
            float wa = bhi(ea), wb = bhi(eb);
            ax = fmaf(wa, blo(ga.x), ax); ay = fmaf(wa, bhi(ga.x), ay);
            az = fmaf(wa, blo(ga.y), az); aw = fmaf(wa, bhi(ga.y), aw);
            bx = fmaf(wb, blo(gb.x), bx); by = fmaf(wb, bhi(gb.x), by);
            bz = fmaf(wb, blo(gb.y), bz); bw = fmaf(wb, bhi(gb.y), bw);
        }
        for (; e < e1; e += 8) {
            int kk = e + g;
            uint ed = (kk < e1) ? ec[kk] : 0u;
            uint2 gv = in[(ed & 0xFFFFu) * 8 + u];
            float wv = bhi(ed);
            ax = fmaf(wv, blo(gv.x), ax); ay = fmaf(wv, bhi(gv.x), ay);
            az = fmaf(wv, blo(gv.y), az); aw = fmaf(wv, bhi(gv.y), aw);
        }
        ax += bx; ay += by; az += bz; aw += bw;
        ax += __shfl_xor(ax, 8);  ay += __shfl_xor(ay, 8);
        az += __shfl_xor(az, 8);  aw += __shfl_xor(aw, 8);
        ax += __shfl_xor(ax, 16); ay += __shfl_xor(ay, 16);
        az += __shfl_xor(az, 16); aw += __shfl_xor(aw, 16);
        ax += __shfl_xor(ax, 32); ay += __shfl_xor(ay, 32);
        az += __shfl_xor(az, 32); aw += __shfl_xor(aw, 32);
        if (g == 0) {
            uint2 res;
            if (PHASE == 1) {
                res.x = (uint)f2bf(2.f * ax) | ((uint)f2bf(2.f * ay) << 16);
                res.y = (uint)f2bf(2.f * az) | ((uint)f2bf(2.f * aw) << 16);
            } else {
                uint2 pu = prev[r * 8 + u];
                float rx = fmaf(1.875f, ax, -1.6875f * blo(pu.x));
                float ry = fmaf(1.875f, ay, -1.6875f * bhi(pu.x));
                float rz = fmaf(1.875f, az, -1.6875f * blo(pu.y));
                float rw = fmaf(1.875f, aw, -1.6875f * bhi(pu.y));
                res.x = (uint)f2bf(rx) | ((uint)f2bf(ry) << 16);
                res.y = (uint)f2bf(rz) | ((uint)f2bf(rw) << 16);
            }
            out[r * 8 + u] = res;
        }
    }
}

// ---------------- batch stats for pos & neg (quarter-blocked bf16 input) ----------------

__global__ __launch_bounds__(256) void stats2_k(const ushort* __restrict__ pos,
                                                const ushort* __restrict__ neg,
                                                float* __restrict__ sums,
                                                float* __restrict__ sumsq) {
    int b = blockIdx.x;            // 626 blocks
    int sign = b >= 313;
    int blk = b - sign * 313;
    const ushort* buf = sign ? neg : pos;
    int c = threadIdx.x & 127, half = threadIdx.x >> 7;
    int qq = c >> 5, cc = c & 31;
    const ushort* base = buf + (long)qq * QSZ16 + cc;
    int r0 = blk * 128;
    int rend = r0 + 128; if (rend > NNODES) rend = NNODES;
    float s = 0.f, s2 = 0.f;
    for (int r = r0 + half; r < rend; r += 2) {
        float v = bf2f(base[r * 32]);
        s += v;
        s2 = fmaf(v, v, s2);
    }
    __shared__ float sh[256], sh2[256];
    sh[threadIdx.x] = s; sh2[threadIdx.x] = s2;
    __syncthreads();
    if (threadIdx.x < 128) {
        int sb = 128 + sign * 128;
        atomicAdd(&sums[sb + c],  sh[c]  + sh[c + 128]);
        atomicAdd(&sumsq[sb + c], sh2[c] + sh2[c + 128]);
    }
}

__global__ void bnfin_k(const float* __restrict__ sum, const float* __restrict__ sumsq,
                        const float* __restrict__ g0, const float* __restrict__ be0,
                        const float* __restrict__ g1, const float* __restrict__ be1,
                        const float* __restrict__ g2, const float* __restrict__ be2,
                        float* __restrict__ bn) {
    int i = threadIdx.x;
    if (i >= 384) return;
    int s = i >> 7, c = i & 127;
    float mean = sum[i] * (1.f / NNODES);
    float var  = sumsq[i] * (1.f / NNODES) - mean * mean;
    const float* g = (s == 0) ? g0 : (s == 1) ? g1 : g2;
    const float* b = (s == 0) ? be0 : (s == 1) ? be1 : be2;
    float sc = g[c] * rsqrtf(var + 1e-5f);
    bn[s * 256 + c]       = sc;
    bn[s * 256 + 128 + c] = b[c] - mean * sc;
}

// ---------------- final MFMA GEMM K=384 with fused BN+PReLU+concat + row-norm ----------------

__global__ __launch_bounds__(256) void mfma_gemm_mlp_k(const ushort* __restrict__ org,
                                                       const ushort* __restrict__ pos,
                                                       const ushort* __restrict__ neg,
                                                       const float* __restrict__ bn,
                                                       const float* __restrict__ prelu_w,
                                                       const ushort* __restrict__ Bp,
                                                       float* __restrict__ Out) {
    int lane = threadIdx.x & 63, wave = threadIdx.x >> 6;
    long rbase = (long)blockIdx.x * 64 + wave * 16;
    int r = lane & 15, kg = lane >> 4;
    float pw = prelu_w[0];
    facc acc[8];
#pragma unroll
    for (int t = 0; t < 8; ++t) acc[t] = (facc){0.f, 0.f, 0.f, 0.f};
    const bfrag* Bq = (const bfrag*)Bp + lane;
#pragma unroll
    for (int ks = 0; ks < 12; ++ks) {
        int c = ks * 32 + kg * 8;          // concat column of first elem
        int s = c >> 7;
        int off = c & 127;
        const ushort* src = (s == 0) ? org : (s == 1) ? pos : neg;
        const uint* srcu = (const uint*)src;
        uint4 u = *(const uint4*)(srcu + (long)(off >> 5) * QSZU + (rbase + r) * 16 + ((off & 31) >> 1));
        float4 sc_lo = *(const float4*)(bn + s * 256 + off);
        float4 sc_hi = *(const float4*)(bn + s * 256 + off + 4);
        float4 sh_lo = *(const float4*)(bn + s * 256 + 128 + off);
        float4 sh_hi = *(const float4*)(bn + s * 256 + 128 + off + 4);
        uint uu[4] = {u.x, u.y, u.z, u.w};
        float scv[8] = {sc_lo.x, sc_lo.y, sc_lo.z, sc_lo.w, sc_hi.x, sc_hi.y, sc_hi.z, sc_hi.w};
        float shv[8] = {sh_lo.x, sh_lo.y, sh_lo.z, sh_lo.w, sh_hi.x, sh_hi.y, sh_hi.z, sh_hi.w};
        bfu av;
#pragma unroll
        for (int k = 0; k < 4; ++k) {
            float vx = __uint_as_float(uu[k] << 16);
            float vy = __uint_as_float(uu[k] & 0xFFFF0000u);
            float ox = fmaf(vx, scv[2 * k],     shv[2 * k]);     ox = (ox >= 0.f) ? ox : pw * ox;
            float oy = fmaf(vy, scv[2 * k + 1], shv[2 * k + 1]); oy = (oy >= 0.f) ? oy : pw * oy;
            av.u[k] = (uint)f2bf(ox) | ((uint)f2bf(oy) << 16);
        }
#pragma unroll
        for (int t = 0; t < 8; ++t)
            acc[t] = __builtin_amdgcn_mfma_f32_16x16x32_bf16(av.v, Bq[(ks * 8 + t) * 64], acc[t], 0, 0, 0);
    }
    long orow = rbase + kg * 4;
#pragma unroll
    for (int j = 0; j < 4; ++j) {
        float ss = 0.f;
#pragma unroll
        for (int t = 0; t < 8; ++t) ss = fmaf(acc[t][j], acc[t][j], ss);
        ss += __shfl_xor(ss, 1);
        ss += __shfl_xor(ss, 2);
        ss += __shfl_xor(ss, 4);
        ss += __shfl_xor(ss, 8);
        float inv = 1.f / fmaxf(sqrtf(ss), 1e-12f);
#pragma unroll
        for (int t = 0; t < 8; ++t)
            Out[(orow + j) * 128 + 16 * t + r] = acc[t][j] * inv;
    }
}

// ---------------- launch ----------------

extern "C" void kernel_launch(void* const* d_in, const int* in_sizes, int n_in,
                              void* d_out, int out_size, void* d_ws, size_t ws_size,
                              hipStream_t stream) {
    const float* x       = (const float*)d_in[0];
    const int*   pos_idx = (const int*)d_in[1];
    const float* pos_w   = (const float*)d_in[2];
    const int*   neg_idx = (const int*)d_in[3];
    const float* neg_w   = (const float*)d_in[4];
    const float* W_org   = (const float*)d_in[5];
    const float* W_pos   = (const float*)d_in[6];
    const float* W_neg   = (const float*)d_in[7];
    const float* g_org   = (const float*)d_in[8];
    const float* b_org   = (const float*)d_in[9];
    const float* g_pos   = (const float*)d_in[10];
    const float* b_pos   = (const float*)d_in[11];
    const float* g_neg   = (const float*)d_in[12];
    const float* b_neg   = (const float*)d_in[13];
    const float* prelu_w = (const float*)d_in[14];
    const float* W_mlp   = (const float*)d_in[15];
    float* out = (float*)d_out;

    char* ws = (char*)d_ws;
    const size_t FB = (size_t)NNODES * 128 * 2;        // 10,240,000 B per feature buffer
    ushort* org0b = (ushort*)(ws);
    ushort* p0b   = (ushort*)(ws + FB);
    ushort* n0b   = (ushort*)(ws + 2 * FB);
    int2* edges   = (int2*)(ws + 3 * FB);              // staging, 14,080,000 B
    uint* ecomp   = (uint*)(ws + 3 * FB + 14080000);   // compressed, 7,040,000 B
    char* small   = ws + 3 * FB + 14080000 + 7040000;
    int* ecnt     = (int*)small;                       // 5000 -> pad 5120
    float* sums   = (float*)(small + 5120);            // 1536
    float* sumsq  = (float*)(small + 5120 + 1536);     // 1536 (memset 0..8192)
    float* bn     = (float*)(small + 8192);            // 3072
    int2* rp2     = (int2*)(small + 8192 + 3072);      // 640,000
    ushort* Wb    = (ushort*)(small + 8192 + 3072 + 640000);   // 196,608 B
    uint* t1_pos  = (uint*)d_out;                      // blocked bf16 scratch halves of d_out
    uint* t1_neg  = (uint*)d_out + 4 * QSZU;

    hipMemsetAsync(small, 0, 8192, stream);

    partition_k<<<79, 256, 0, stream>>>(pos_idx, pos_w, neg_idx, neg_w, ecnt, edges);
    bucket_csr_k<<<2 * NBUCK, 256, 0, stream>>>(ecnt, edges, ecomp, rp2);
    pack_all_k<<<384, 256, 0, stream>>>(W_org, W_pos, W_neg, W_mlp, Wb);

    mfma_gemm3_k<<<625, 256, 0, stream>>>(x, Wb, Wb + 16384, Wb + 32768,
                                          org0b, p0b, n0b, sums, sumsq);

    // Jacobi (a=b=1, K=3): x1 = 2*A@x0 ; x2 = 1.875*A@x1 - 1.6875*x0
    spmmq_k<1><<<40000, 256, 0, stream>>>(rp2, ecomp,
        (const uint*)p0b, (const uint*)n0b, nullptr, nullptr, t1_pos, t1_neg);
    spmmq_k<2><<<40000, 256, 0, stream>>>(rp2, ecomp,
        t1_pos, t1_neg, (const uint*)p0b, (const uint*)n0b, (uint*)p0b, (uint*)n0b);

    stats2_k<<<626, 256, 0, stream>>>(p0b, n0b, sums, sumsq);
    bnfin_k<<<1, 384, 0, stream>>>(sums, sumsq, g_org, b_org, g_pos, b_pos, g_neg, b_neg, bn);
    mfma_gemm_mlp_k<<<625, 256, 0, stream>>>(org0b, p0b, n0b, bn, prelu_w, Wb + 49152, out);

    (void)in_sizes; (void)n_in; (void)out_size; (void)ws_size;
}

// Round 10
// 264.870 us; speedup vs baseline: 1.4167x; 1.2204x over previous
//
#include <hip/hip_runtime.h>

#define NNODES 40000
#define NEDGE  640000
#define NBUCK  625          // buckets per sign, 64 rows each
#define ECAP   1408         // per-bucket capacity (mean 1024, sd ~32)
#define QSZ16  1280000      // ushorts per quarter table (40000*32)
#define QSZU   640000       // uints per quarter table

typedef __attribute__((ext_vector_type(8))) short bfrag;
typedef __attribute__((ext_vector_type(4))) float facc;

union bfu { bfrag v; uint u[4]; };

__device__ inline ushort f2bf(float f) {
    uint u = __float_as_uint(f);
    return (ushort)((u + 0x7FFFu + ((u >> 16) & 1u)) >> 16);
}
__device__ inline float bf2f(ushort h) {
    return __uint_as_float(((uint)h) << 16);
}
__device__ inline float blo(uint u) { return __uint_as_float(u << 16); }
__device__ inline float bhi(uint u) { return __uint_as_float(u & 0xFFFF0000u); }

// ---------------- edge partition into 64-row buckets ----------------

__global__ __launch_bounds__(256) void partition_k(const int* __restrict__ pos_idx,
                                                   const float* __restrict__ pos_w,
                                                   const int* __restrict__ neg_idx,
                                                   const float* __restrict__ neg_w,
                                                   int* __restrict__ ecnt,
                                                   int2* __restrict__ edges) {
    __shared__ int lhist[2 * NBUCK];
    __shared__ int lbase[2 * NBUCK];
    long g0 = (long)blockIdx.x * 16384;
    for (int i = threadIdx.x; i < 2 * NBUCK; i += 256) lhist[i] = 0;
    __syncthreads();
    for (int i = 0; i < 64; ++i) {
        long g = g0 + i * 256 + threadIdx.x;
        if (g < 2 * NEDGE) {
            int sign = g >= NEDGE;
            int e = (int)(g - (long)sign * NEDGE);
            int row = sign ? neg_idx[e] : pos_idx[e];
            atomicAdd(&lhist[sign * NBUCK + (row >> 6)], 1);
        }
    }
    __syncthreads();
    for (int b = threadIdx.x; b < 2 * NBUCK; b += 256) {
        int c = lhist[b];
        lbase[b] = c ? atomicAdd(&ecnt[b], c) : 0;
        lhist[b] = 0;
    }
    __syncthreads();
    for (int i = 0; i < 64; ++i) {
        long g = g0 + i * 256 + threadIdx.x;
        if (g < 2 * NEDGE) {
            int sign = g >= NEDGE;
            int e = (int)(g - (long)sign * NEDGE);
            int row = sign ? neg_idx[e] : pos_idx[e];
            int col = sign ? neg_idx[NEDGE + e] : pos_idx[NEDGE + e];
            float wv = sign ? neg_w[e] : pos_w[e];
            int b = sign * NBUCK + (row >> 6);
            int off = lbase[b] + atomicAdd(&lhist[b], 1);
            if (off < ECAP)
                edges[(long)b * ECAP + off] =
                    make_int2((int)((uint)col | ((uint)(row & 63) << 16)), __float_as_int(wv));
        }
    }
}

// ---------------- bucket-local counting sort -> compressed CSR ----------------

__global__ __launch_bounds__(256) void bucket_csr_k(const int* __restrict__ ecnt,
                                                    const int2* __restrict__ edges,
                                                    uint* __restrict__ ecomp,
                                                    int2* __restrict__ rp2) {
    __shared__ int2 stage[ECAP];
    __shared__ int hist[64];
    __shared__ int base_[64];
    int b = blockIdx.x;
    int tid = threadIdx.x;
    int cnt = ecnt[b]; if (cnt > ECAP) cnt = ECAP;
    if (tid < 64) hist[tid] = 0;
    __syncthreads();
    long e0 = (long)b * ECAP;
    for (int i = tid; i < cnt; i += 256) {
        int2 e = edges[e0 + i];
        stage[i] = e;
        atomicAdd(&hist[((uint)e.x >> 16) & 63u], 1);
    }
    __syncthreads();
    if (tid < 64) {
        int v = hist[tid];
        int s = v;
#pragma unroll
        for (int off = 1; off < 64; off <<= 1) {
            int t = __shfl_up(s, off);
            if ((tid & 63) >= off) s += t;
        }
        int excl = s - v;
        base_[tid] = excl;
        int sign = b >= NBUCK;
        int r = (b - sign * NBUCK) * 64 + tid;
        rp2[sign * NNODES + r] = make_int2((int)(e0 + excl), (int)(e0 + excl + v));
        hist[tid] = 0;   // reuse as cursor
    }
    __syncthreads();
    for (int i = tid; i < cnt; i += 256) {
        int2 e = stage[i];
        int rl = ((uint)e.x >> 16) & 63u;
        int pos = base_[rl] + atomicAdd(&hist[rl], 1);
        ecomp[e0 + pos] = ((uint)e.x & 0xFFFFu) |
                          ((uint)f2bf(__int_as_float(e.y)) << 16);
    }
}

// ---------------- pack all W into MFMA B-fragment order ----------------

__global__ __launch_bounds__(256) void pack_all_k(const float* __restrict__ Wo,
                                                  const float* __restrict__ Wp,
                                                  const float* __restrict__ Wn,
                                                  const float* __restrict__ Wm,
                                                  ushort* __restrict__ out) {
    int idx = blockIdx.x * 256 + threadIdx.x;      // 0..98303
    const float* W;
    ushort* dst;
    int local;
    if (idx < 49152) {
        int m = idx >> 14;
        local = idx & 16383;
        W = (m == 0) ? Wo : (m == 1) ? Wp : Wn;
        dst = out + m * 16384;
    } else {
        local = idx - 49152;
        W = Wm;
        dst = out + 49152;
    }
    int j = local & 7, l = (local >> 3) & 63, t = (local >> 9) & 7, ks = local >> 12;
    int k = ks * 32 + (l >> 4) * 8 + j;
    int c = (l & 15) + 16 * t;
    dst[local] = f2bf(W[k * 128 + c]);
}

// ---------------- fused triple MFMA GEMM: x(f32) @ {W_org,W_pos,W_neg} ----------------
// outputs quarter-blocked bf16; fused per-channel stats for org.

__global__ __launch_bounds__(256) void mfma_gemm3_k(const float* __restrict__ x,
                                                    const ushort* __restrict__ B0,
                                                    const ushort* __restrict__ B1,
                                                    const ushort* __restrict__ B2,
                                                    ushort* __restrict__ O0,
                                                    ushort* __restrict__ O1,
                                                    ushort* __restrict__ O2,
                                                    float* __restrict__ sums,
                                                    float* __restrict__ sumsq) {
    __shared__ float cs[128], cq[128];
    int tid = threadIdx.x;
    int lane = tid & 63, wave = tid >> 6;
    if (tid < 128) { cs[tid] = 0.f; cq[tid] = 0.f; }
    __syncthreads();
    long rbase = (long)blockIdx.x * 64 + wave * 16;
    int r = lane & 15, kg = lane >> 4;
    const float* xr = x + (rbase + r) * 128 + kg * 8;
    bfrag a[4];
#pragma unroll
    for (int ks = 0; ks < 4; ++ks) {
        float4 lo = *(const float4*)(xr + ks * 32);
        float4 hi = *(const float4*)(xr + ks * 32 + 4);
        bfu t;
        t.u[0] = (uint)f2bf(lo.x) | ((uint)f2bf(lo.y) << 16);
        t.u[1] = (uint)f2bf(lo.z) | ((uint)f2bf(lo.w) << 16);
        t.u[2] = (uint)f2bf(hi.x) | ((uint)f2bf(hi.y) << 16);
        t.u[3] = (uint)f2bf(hi.z) | ((uint)f2bf(hi.w) << 16);
        a[ks] = t.v;
    }
    const ushort* Bs[3] = {B0, B1, B2};
    ushort* Os[3] = {O0, O1, O2};
    long orow = rbase + kg * 4;
#pragma unroll
    for (int m = 0; m < 3; ++m) {
        const bfrag* Bq = (const bfrag*)Bs[m] + lane;
        facc acc[8];
#pragma unroll
        for (int t = 0; t < 8; ++t) acc[t] = (facc){0.f, 0.f, 0.f, 0.f};
#pragma unroll
        for (int ks = 0; ks < 4; ++ks)
#pragma unroll
            for (int t = 0; t < 8; ++t)
                acc[t] = __builtin_amdgcn_mfma_f32_16x16x32_bf16(a[ks], Bq[(ks * 8 + t) * 64], acc[t], 0, 0, 0);
        ushort* O = Os[m];
#pragma unroll
        for (int t = 0; t < 8; ++t) {
            float s_ = 0.f, q_ = 0.f;
            // channel c = 16t + r -> blocked: q = t>>1, cc = (t&1)*16 + r
            long qb = (long)(t >> 1) * QSZ16 + (t & 1) * 16 + r;
#pragma unroll
            for (int j = 0; j < 4; ++j) {
                ushort bv = f2bf(acc[t][j]);
                O[qb + (orow + j) * 32] = bv;
                if (m == 0) {
                    float fv = bf2f(bv);
                    s_ += fv;
                    q_ = fmaf(fv, fv, q_);
                }
            }
            if (m == 0) {
                atomicAdd(&cs[16 * t + r], s_);
                atomicAdd(&cq[16 * t + r], q_);
            }
        }
    }
    __syncthreads();
    if (tid < 128) {
        atomicAdd(&sums[tid], cs[tid]);
        atomicAdd(&sumsq[tid], cq[tid]);
    }
}

// ---------------- quarter-blocked SpMM: 8 rows/wave, no cross-lane reduce ----------
// grp = blockIdx.x & 7 pins each (sign,quarter) group to one XCD (2.56 MB table
// L2-resident). Wave = 8 rows x 8 lanes; each 8-lane group walks its own row's
// edges serially, accumulating 4 channels in registers -> zero shfl, fully
// coalesced 512 B wave stores. 2-edge unroll keeps 2 gathers in flight/group.

template<int PHASE>
__global__ __launch_bounds__(256) void spmmg_k(const int2* __restrict__ rp2,
                                               const uint* __restrict__ ec,
                                               const uint* __restrict__ p_in,
                                               const uint* __restrict__ n_in,
                                               const uint* __restrict__ p_prev,
                                               const uint* __restrict__ n_prev,
                                               uint* __restrict__ p_out,
                                               uint* __restrict__ n_out) {
    int grp = blockIdx.x & 7;
    int rg  = blockIdx.x >> 3;          // 0..1249
    int sign = grp >> 2, q = grp & 3;
    int tid = threadIdx.x;
    int w = tid >> 6, lane = tid & 63;
    int u = lane & 7;                   // uint2 index (4 bf16 channels)
    int rl = lane >> 3;                 // row within wave
    const uint2* in  = (const uint2*)((sign ? n_in : p_in) + q * QSZU);
    uint2* out = (uint2*)((sign ? n_out : p_out) + q * QSZU);
    int r = rg * 32 + w * 8 + rl;
    int2 se = rp2[sign * NNODES + r];
    float ax = 0.f, ay = 0.f, az = 0.f, aw = 0.f;
    float bx = 0.f, by = 0.f, bz = 0.f, bw = 0.f;
    int e = se.x, e1 = se.y;
    for (; e + 2 <= e1; e += 2) {
        uint ea = ec[e], eb = ec[e + 1];
        uint2 ga = in[(ea & 0xFFFFu) * 8 + u];
        uint2 gb = in[(eb & 0xFFFFu) * 8 + u];
        float wa = bhi(ea), wb = bhi(eb);
        ax = fmaf(wa, blo(ga.x), ax); ay = fmaf(wa, bhi(ga.x), ay);
        az = fmaf(wa, blo(ga.y), az); aw = fmaf(wa, bhi(ga.y), aw);
        bx = fmaf(wb, blo(gb.x), bx); by = fmaf(wb, bhi(gb.x), by);
        bz = fmaf(wb, blo(gb.y), bz); bw = fmaf(wb, bhi(gb.y), bw);
    }
    if (e < e1) {
        uint ea = ec[e];
        uint2 ga = in[(ea & 0xFFFFu) * 8 + u];
        float wa = bhi(ea);
        ax = fmaf(wa, blo(ga.x), ax); ay = fmaf(wa, bhi(ga.x), ay);
        az = fmaf(wa, blo(ga.y), az); aw = fmaf(wa, bhi(ga.y), aw);
    }
    ax += bx; ay += by; az += bz; aw += bw;
    uint2 res;
    if (PHASE == 1) {
        res.x = (uint)f2bf(2.f * ax) | ((uint)f2bf(2.f * ay) << 16);
        res.y = (uint)f2bf(2.f * az) | ((uint)f2bf(2.f * aw) << 16);
    } else {
        const uint2* prev = (const uint2*)((sign ? n_prev : p_prev) + q * QSZU);
        uint2 pu = prev[r * 8 + u];
        float rx = fmaf(1.875f, ax, -1.6875f * blo(pu.x));
        float ry = fmaf(1.875f, ay, -1.6875f * bhi(pu.x));
        float rz = fmaf(1.875f, az, -1.6875f * blo(pu.y));
        float rw = fmaf(1.875f, aw, -1.6875f * bhi(pu.y));
        res.x = (uint)f2bf(rx) | ((uint)f2bf(ry) << 16);
        res.y = (uint)f2bf(rz) | ((uint)f2bf(rw) << 16);
    }
    out[r * 8 + u] = res;
}

// ---------------- batch stats for pos & neg (quarter-blocked bf16 input) ----------------

__global__ __launch_bounds__(256) void stats2_k(const ushort* __restrict__ pos,
                                                const ushort* __restrict__ neg,
                                                float* __restrict__ sums,
                                                float* __restrict__ sumsq) {
    int b = blockIdx.x;            // 626 blocks
    int sign = b >= 313;
    int blk = b - sign * 313;
    const ushort* buf = sign ? neg : pos;
    int c = threadIdx.x & 127, half = threadIdx.x >> 7;
    int qq = c >> 5, cc = c & 31;
    const ushort* base = buf + (long)qq * QSZ16 + cc;
    int r0 = blk * 128;
    int rend = r0 + 128; if (rend > NNODES) rend = NNODES;
    float s = 0.f, s2 = 0.f;
    for (int r = r0 + half; r < rend; r += 2) {
        float v = bf2f(base[r * 32]);
        s += v;
        s2 = fmaf(v, v, s2);
    }
    __shared__ float sh[256], sh2[256];
    sh[threadIdx.x] = s; sh2[threadIdx.x] = s2;
    __syncthreads();
    if (threadIdx.x < 128) {
        int sb = 128 + sign * 128;
        atomicAdd(&sums[sb + c],  sh[c]  + sh[c + 128]);
        atomicAdd(&sumsq[sb + c], sh2[c] + sh2[c + 128]);
    }
}

__global__ void bnfin_k(const float* __restrict__ sum, const float* __restrict__ sumsq,
                        const float* __restrict__ g0, const float* __restrict__ be0,
                        const float* __restrict__ g1, const float* __restrict__ be1,
                        const float* __restrict__ g2, const float* __restrict__ be2,
                        float* __restrict__ bn) {
    int i = threadIdx.x;
    if (i >= 384) return;
    int s = i >> 7, c = i & 127;
    float mean = sum[i] * (1.f / NNODES);
    float var  = sumsq[i] * (1.f / NNODES) - mean * mean;
    const float* g = (s == 0) ? g0 : (s == 1) ? g1 : g2;
    const float* b = (s == 0) ? be0 : (s == 1) ? be1 : be2;
    float sc = g[c] * rsqrtf(var + 1e-5f);
    bn[s * 256 + c]       = sc;
    bn[s * 256 + 128 + c] = b[c] - mean * sc;
}

// ---------------- final MFMA GEMM K=384 with fused BN+PReLU+concat + row-norm ----------------

__global__ __launch_bounds__(256) void mfma_gemm_mlp_k(const ushort* __restrict__ org,
                                                       const ushort* __restrict__ pos,
                                                       const ushort* __restrict__ neg,
                                                       const float* __restrict__ bn,
                                                       const float* __restrict__ prelu_w,
                                                       const ushort* __restrict__ Bp,
                                                       float* __restrict__ Out) {
    int lane = threadIdx.x & 63, wave = threadIdx.x >> 6;
    long rbase = (long)blockIdx.x * 64 + wave * 16;
    int r = lane & 15, kg = lane >> 4;
    float pw = prelu_w[0];
    facc acc[8];
#pragma unroll
    for (int t = 0; t < 8; ++t) acc[t] = (facc){0.f, 0.f, 0.f, 0.f};
    const bfrag* Bq = (const bfrag*)Bp + lane;
#pragma unroll
    for (int ks = 0; ks < 12; ++ks) {
        int c = ks * 32 + kg * 8;          // concat column of first elem
        int s = c >> 7;
        int off = c & 127;
        const ushort* src = (s == 0) ? org : (s == 1) ? pos : neg;
        const uint* srcu = (const uint*)src;
        uint4 u = *(const uint4*)(srcu + (long)(off >> 5) * QSZU + (rbase + r) * 16 + ((off & 31) >> 1));
        float4 sc_lo = *(const float4*)(bn + s * 256 + off);
        float4 sc_hi = *(const float4*)(bn + s * 256 + off + 4);
        float4 sh_lo = *(const float4*)(bn + s * 256 + 128 + off);
        float4 sh_hi = *(const float4*)(bn + s * 256 + 128 + off + 4);
        uint uu[4] = {u.x, u.y, u.z, u.w};
        float scv[8] = {sc_lo.x, sc_lo.y, sc_lo.z, sc_lo.w, sc_hi.x, sc_hi.y, sc_hi.z, sc_hi.w};
        float shv[8] = {sh_lo.x, sh_lo.y, sh_lo.z, sh_lo.w, sh_hi.x, sh_hi.y, sh_hi.z, sh_hi.w};
        bfu av;
#pragma unroll
        for (int k = 0; k < 4; ++k) {
            float vx = __uint_as_float(uu[k] << 16);
            float vy = __uint_as_float(uu[k] & 0xFFFF0000u);
            float ox = fmaf(vx, scv[2 * k],     shv[2 * k]);     ox = (ox >= 0.f) ? ox : pw * ox;
            float oy = fmaf(vy, scv[2 * k + 1], shv[2 * k + 1]); oy = (oy >= 0.f) ? oy : pw * oy;
            av.u[k] = (uint)f2bf(ox) | ((uint)f2bf(oy) << 16);
        }
#pragma unroll
        for (int t = 0; t < 8; ++t)
            acc[t] = __builtin_amdgcn_mfma_f32_16x16x32_bf16(av.v, Bq[(ks * 8 + t) * 64], acc[t], 0, 0, 0);
    }
    long orow = rbase + kg * 4;
#pragma unroll
    for (int j = 0; j < 4; ++j) {
        float ss = 0.f;
#pragma unroll
        for (int t = 0; t < 8; ++t) ss = fmaf(acc[t][j], acc[t][j], ss);
        ss += __shfl_xor(ss, 1);
        ss += __shfl_xor(ss, 2);
        ss += __shfl_xor(ss, 4);
        ss += __shfl_xor(ss, 8);
        float inv = 1.f / fmaxf(sqrtf(ss), 1e-12f);
#pragma unroll
        for (int t = 0; t < 8; ++t)
            Out[(orow + j) * 128 + 16 * t + r] = acc[t][j] * inv;
    }
}

// ---------------- launch ----------------

extern "C" void kernel_launch(void* const* d_in, const int* in_sizes, int n_in,
                              void* d_out, int out_size, void* d_ws, size_t ws_size,
                              hipStream_t stream) {
    const float* x       = (const float*)d_in[0];
    const int*   pos_idx = (const int*)d_in[1];
    const float* pos_w   = (const float*)d_in[2];
    const int*   neg_idx = (const int*)d_in[3];
    const float* neg_w   = (const float*)d_in[4];
    const float* W_org   = (const float*)d_in[5];
    const float* W_pos   = (const float*)d_in[6];
    const float* W_neg   = (const float*)d_in[7];
    const float* g_org   = (const float*)d_in[8];
    const float* b_org   = (const float*)d_in[9];
    const float* g_pos   = (const float*)d_in[10];
    const float* b_pos   = (const float*)d_in[11];
    const float* g_neg   = (const float*)d_in[12];
    const float* b_neg   = (const float*)d_in[13];
    const float* prelu_w = (const float*)d_in[14];
    const float* W_mlp   = (const float*)d_in[15];
    float* out = (float*)d_out;

    char* ws = (char*)d_ws;
    const size_t FB = (size_t)NNODES * 128 * 2;        // 10,240,000 B per feature buffer
    ushort* org0b = (ushort*)(ws);
    ushort* p0b   = (ushort*)(ws + FB);
    ushort* n0b   = (ushort*)(ws + 2 * FB);
    int2* edges   = (int2*)(ws + 3 * FB);              // staging, 14,080,000 B
    uint* ecomp   = (uint*)(ws + 3 * FB + 14080000);   // compressed, 7,040,000 B
    char* small   = ws + 3 * FB + 14080000 + 7040000;
    int* ecnt     = (int*)small;                       // 5000 -> pad 5120
    float* sums   = (float*)(small + 5120);            // 1536
    float* sumsq  = (float*)(small + 5120 + 1536);     // 1536 (memset 0..8192)
    float* bn     = (float*)(small + 8192);            // 3072
    int2* rp2     = (int2*)(small + 8192 + 3072);      // 640,000
    ushort* Wb    = (ushort*)(small + 8192 + 3072 + 640000);   // 196,608 B
    uint* t1_pos  = (uint*)d_out;                      // blocked bf16 scratch halves of d_out
    uint* t1_neg  = (uint*)d_out + 4 * QSZU;

    hipMemsetAsync(small, 0, 8192, stream);

    partition_k<<<79, 256, 0, stream>>>(pos_idx, pos_w, neg_idx, neg_w, ecnt, edges);
    bucket_csr_k<<<2 * NBUCK, 256, 0, stream>>>(ecnt, edges, ecomp, rp2);
    pack_all_k<<<384, 256, 0, stream>>>(W_org, W_pos, W_neg, W_mlp, Wb);

    mfma_gemm3_k<<<625, 256, 0, stream>>>(x, Wb, Wb + 16384, Wb + 32768,
                                          org0b, p0b, n0b, sums, sumsq);

    // Jacobi (a=b=1, K=3): x1 = 2*A@x0 ; x2 = 1.875*A@x1 - 1.6875*x0
    spmmg_k<1><<<10000, 256, 0, stream>>>(rp2, ecomp,
        (const uint*)p0b, (const uint*)n0b, nullptr, nullptr, t1_pos, t1_neg);
    spmmg_k<2><<<10000, 256, 0, stream>>>(rp2, ecomp,
        t1_pos, t1_neg, (const uint*)p0b, (const uint*)n0b, (uint*)p0b, (uint*)n0b);

    stats2_k<<<626, 256, 0, stream>>>(p0b, n0b, sums, sumsq);
    bnfin_k<<<1, 384, 0, stream>>>(sums, sumsq, g_org, b_org, g_pos, b_pos, g_neg, b_neg, bn);
    mfma_gemm_mlp_k<<<625, 256, 0, stream>>>(org0b, p0b, n0b, bn, prelu_w, Wb + 49152, out);

    (void)in_sizes; (void)n_in; (void)out_size; (void)ws_size;
}

// Round 11
// 223.932 us; speedup vs baseline: 1.6757x; 1.1828x over previous
//
#include <hip/hip_runtime.h>

#define NNODES 40000
#define NEDGE  640000
#define NBUCK  625          // buckets per sign, 64 rows each
#define ECAP   1408         // per-bucket capacity (mean 1024, sd ~32)
#define QSZ16  1280000      // ushorts per quarter table (40000*32)
#define QSZU   640000       // uints per quarter table
#define PCHUNK 4096         // edges per partition block
#define PBLKS  313          // ceil(2*NEDGE / PCHUNK)

typedef __attribute__((ext_vector_type(8))) short bfrag;
typedef __attribute__((ext_vector_type(4))) float facc;

union bfu { bfrag v; uint u[4]; };

__device__ inline ushort f2bf(float f) {
    uint u = __float_as_uint(f);
    return (ushort)((u + 0x7FFFu + ((u >> 16) & 1u)) >> 16);
}
__device__ inline float bf2f(ushort h) {
    return __uint_as_float(((uint)h) << 16);
}
__device__ inline float blo(uint u) { return __uint_as_float(u << 16); }
__device__ inline float bhi(uint u) { return __uint_as_float(u & 0xFFFF0000u); }

// ---------------- edge partition into 64-row buckets ----------------
// 313 blocks x 4096-edge chunks (4x TLP vs 79x16384); rows cached in LDS
// between the histogram pass and the scatter pass.

__global__ __launch_bounds__(256) void partition_k(const int* __restrict__ pos_idx,
                                                   const float* __restrict__ pos_w,
                                                   const int* __restrict__ neg_idx,
                                                   const float* __restrict__ neg_w,
                                                   int* __restrict__ ecnt,
                                                   int2* __restrict__ edges) {
    __shared__ int lhist[2 * NBUCK];
    __shared__ int lbase[2 * NBUCK];
    __shared__ ushort rows_s[PCHUNK];
    long g0 = (long)blockIdx.x * PCHUNK;
    for (int i = threadIdx.x; i < 2 * NBUCK; i += 256) lhist[i] = 0;
    __syncthreads();
#pragma unroll
    for (int i = 0; i < 16; ++i) {
        long g = g0 + i * 256 + threadIdx.x;
        if (g < 2 * NEDGE) {
            int sign = g >= NEDGE;
            int e = (int)(g - (long)sign * NEDGE);
            int row = sign ? neg_idx[e] : pos_idx[e];
            rows_s[i * 256 + threadIdx.x] = (ushort)row;
            atomicAdd(&lhist[sign * NBUCK + (row >> 6)], 1);
        }
    }
    __syncthreads();
    for (int b = threadIdx.x; b < 2 * NBUCK; b += 256) {
        int c = lhist[b];
        lbase[b] = c ? atomicAdd(&ecnt[b], c) : 0;
        lhist[b] = 0;
    }
    __syncthreads();
#pragma unroll
    for (int i = 0; i < 16; ++i) {
        long g = g0 + i * 256 + threadIdx.x;
        if (g < 2 * NEDGE) {
            int sign = g >= NEDGE;
            int e = (int)(g - (long)sign * NEDGE);
            int row = rows_s[i * 256 + threadIdx.x];
            int col = sign ? neg_idx[NEDGE + e] : pos_idx[NEDGE + e];
            float wv = sign ? neg_w[e] : pos_w[e];
            int b = sign * NBUCK + (row >> 6);
            int off = lbase[b] + atomicAdd(&lhist[b], 1);
            if (off < ECAP)
                edges[(long)b * ECAP + off] =
                    make_int2((int)((uint)col | ((uint)(row & 63) << 16)), __float_as_int(wv));
        }
    }
}

// ---------------- bucket-local counting sort -> compressed CSR ----------------

__global__ __launch_bounds__(256) void bucket_csr_k(const int* __restrict__ ecnt,
                                                    const int2* __restrict__ edges,
                                                    uint* __restrict__ ecomp,
                                                    int2* __restrict__ rp2) {
    __shared__ int2 stage[ECAP];
    __shared__ int hist[64];
    __shared__ int base_[64];
    int b = blockIdx.x;
    int tid = threadIdx.x;
    int cnt = ecnt[b]; if (cnt > ECAP) cnt = ECAP;
    if (tid < 64) hist[tid] = 0;
    __syncthreads();
    long e0 = (long)b * ECAP;
    for (int i = tid; i < cnt; i += 256) {
        int2 e = edges[e0 + i];
        stage[i] = e;
        atomicAdd(&hist[((uint)e.x >> 16) & 63u], 1);
    }
    __syncthreads();
    if (tid < 64) {
        int v = hist[tid];
        int s = v;
#pragma unroll
        for (int off = 1; off < 64; off <<= 1) {
            int t = __shfl_up(s, off);
            if ((tid & 63) >= off) s += t;
        }
        int excl = s - v;
        base_[tid] = excl;
        int sign = b >= NBUCK;
        int r = (b - sign * NBUCK) * 64 + tid;
        rp2[sign * NNODES + r] = make_int2((int)(e0 + excl), (int)(e0 + excl + v));
        hist[tid] = 0;   // reuse as cursor
    }
    __syncthreads();
    for (int i = tid; i < cnt; i += 256) {
        int2 e = stage[i];
        int rl = ((uint)e.x >> 16) & 63u;
        int pos = base_[rl] + atomicAdd(&hist[rl], 1);
        ecomp[e0 + pos] = ((uint)e.x & 0xFFFFu) |
                          ((uint)f2bf(__int_as_float(e.y)) << 16);
    }
}

// ---------------- pack all W into MFMA B-fragment order ----------------

__global__ __launch_bounds__(256) void pack_all_k(const float* __restrict__ Wo,
                                                  const float* __restrict__ Wp,
                                                  const float* __restrict__ Wn,
                                                  const float* __restrict__ Wm,
                                                  ushort* __restrict__ out) {
    int idx = blockIdx.x * 256 + threadIdx.x;      // 0..98303
    const float* W;
    ushort* dst;
    int local;
    if (idx < 49152) {
        int m = idx >> 14;
        local = idx & 16383;
        W = (m == 0) ? Wo : (m == 1) ? Wp : Wn;
        dst = out + m * 16384;
    } else {
        local = idx - 49152;
        W = Wm;
        dst = out + 49152;
    }
    int j = local & 7, l = (local >> 3) & 63, t = (local >> 9) & 7, ks = local >> 12;
    int k = ks * 32 + (l >> 4) * 8 + j;
    int c = (l & 15) + 16 * t;
    dst[local] = f2bf(W[k * 128 + c]);
}

// ---------------- fused triple MFMA GEMM: x(f32) @ {W_org,W_pos,W_neg} ----------------
// outputs quarter-blocked bf16; fused per-channel stats for org.

__global__ __launch_bounds__(256) void mfma_gemm3_k(const float* __restrict__ x,
                                                    const ushort* __restrict__ B0,
                                                    const ushort* __restrict__ B1,
                                                    const ushort* __restrict__ B2,
                                                    ushort* __restrict__ O0,
                                                    ushort* __restrict__ O1,
                                                    ushort* __restrict__ O2,
                                                    float* __restrict__ sums,
                                                    float* __restrict__ sumsq) {
    __shared__ float cs[128], cq[128];
    int tid = threadIdx.x;
    int lane = tid & 63, wave = tid >> 6;
    if (tid < 128) { cs[tid] = 0.f; cq[tid] = 0.f; }
    __syncthreads();
    long rbase = (long)blockIdx.x * 64 + wave * 16;
    int r = lane & 15, kg = lane >> 4;
    const float* xr = x + (rbase + r) * 128 + kg * 8;
    bfrag a[4];
#pragma unroll
    for (int ks = 0; ks < 4; ++ks) {
        float4 lo = *(const float4*)(xr + ks * 32);
        float4 hi = *(const float4*)(xr + ks * 32 + 4);
        bfu t;
        t.u[0] = (uint)f2bf(lo.x) | ((uint)f2bf(lo.y) << 16);
        t.u[1] = (uint)f2bf(lo.z) | ((uint)f2bf(lo.w) << 16);
        t.u[2] = (uint)f2bf(hi.x) | ((uint)f2bf(hi.y) << 16);
        t.u[3] = (uint)f2bf(hi.z) | ((uint)f2bf(hi.w) << 16);
        a[ks] = t.v;
    }
    const ushort* Bs[3] = {B0, B1, B2};
    ushort* Os[3] = {O0, O1, O2};
    long orow = rbase + kg * 4;
#pragma unroll
    for (int m = 0; m < 3; ++m) {
        const bfrag* Bq = (const bfrag*)Bs[m] + lane;
        facc acc[8];
#pragma unroll
        for (int t = 0; t < 8; ++t) acc[t] = (facc){0.f, 0.f, 0.f, 0.f};
#pragma unroll
        for (int ks = 0; ks < 4; ++ks)
#pragma unroll
            for (int t = 0; t < 8; ++t)
                acc[t] = __builtin_amdgcn_mfma_f32_16x16x32_bf16(a[ks], Bq[(ks * 8 + t) * 64], acc[t], 0, 0, 0);
        ushort* O = Os[m];
#pragma unroll
        for (int t = 0; t < 8; ++t) {
            float s_ = 0.f, q_ = 0.f;
            // channel c = 16t + r -> blocked: q = t>>1, cc = (t&1)*16 + r
            long qb = (long)(t >> 1) * QSZ16 + (t & 1) * 16 + r;
#pragma unroll
            for (int j = 0; j < 4; ++j) {
                ushort bv = f2bf(acc[t][j]);
                O[qb + (orow + j) * 32] = bv;
                if (m == 0) {
                    float fv = bf2f(bv);
                    s_ += fv;
                    q_ = fmaf(fv, fv, q_);
                }
            }
            if (m == 0) {
                atomicAdd(&cs[16 * t + r], s_);
                atomicAdd(&cq[16 * t + r], q_);
            }
        }
    }
    __syncthreads();
    if (tid < 128) {
        atomicAdd(&sums[tid], cs[tid]);
        atomicAdd(&sumsq[tid], cq[tid]);
    }
}

// ---------------- quarter-blocked SpMM: 8 rows/wave, no cross-lane reduce ----------
// grp = blockIdx.x & 7 pins each (sign,quarter) group to one XCD (2.56 MB table
// L2-resident). Wave = 8 rows x 8 lanes; each 8-lane group walks its own row's
// edges serially, accumulating 4 channels in registers -> zero shfl, fully
// coalesced 512 B wave stores. 2-edge unroll keeps 2 gathers in flight/group.

template<int PHASE>
__global__ __launch_bounds__(256) void spmmg_k(const int2* __restrict__ rp2,
                                               const uint* __restrict__ ec,
                                               const uint* __restrict__ p_in,
                                               const uint* __restrict__ n_in,
                                               const uint* __restrict__ p_prev,
                                               const uint* __restrict__ n_prev,
                                               uint* __restrict__ p_out,
                                               uint* __restrict__ n_out) {
    int grp = blockIdx.x & 7;
    int rg  = blockIdx.x >> 3;          // 0..1249
    int sign = grp >> 2, q = grp & 3;
    int tid = threadIdx.x;
    int w = tid >> 6, lane = tid & 63;
    int u = lane & 7;                   // uint2 index (4 bf16 channels)
    int rl = lane >> 3;                 // row within wave
    const uint2* in  = (const uint2*)((sign ? n_in : p_in) + q * QSZU);
    uint2* out = (uint2*)((sign ? n_out : p_out) + q * QSZU);
    int r = rg * 32 + w * 8 + rl;
    int2 se = rp2[sign * NNODES + r];
    float ax = 0.f, ay = 0.f, az = 0.f, aw = 0.f;
    float bx = 0.f, by = 0.f, bz = 0.f, bw = 0.f;
    int e = se.x, e1 = se.y;
    for (; e + 2 <= e1; e += 2) {
        uint ea = ec[e], eb = ec[e + 1];
        uint2 ga = in[(ea & 0xFFFFu) * 8 + u];
        uint2 gb = in[(eb & 0xFFFFu) * 8 + u];
        float wa = bhi(ea), wb = bhi(eb);
        ax = fmaf(wa, blo(ga.x), ax); ay = fmaf(wa, bhi(ga.x), ay);
        az = fmaf(wa, blo(ga.y), az); aw = fmaf(wa, bhi(ga.y), aw);
        bx = fmaf(wb, blo(gb.x), bx); by = fmaf(wb, bhi(gb.x), by);
        bz = fmaf(wb, blo(gb.y), bz); bw = fmaf(wb, bhi(gb.y), bw);
    }
    if (e < e1) {
        uint ea = ec[e];
        uint2 ga = in[(ea & 0xFFFFu) * 8 + u];
        float wa = bhi(ea);
        ax = fmaf(wa, blo(ga.x), ax); ay = fmaf(wa, bhi(ga.x), ay);
        az = fmaf(wa, blo(ga.y), az); aw = fmaf(wa, bhi(ga.y), aw);
    }
    ax += bx; ay += by; az += bz; aw += bw;
    uint2 res;
    if (PHASE == 1) {
        res.x = (uint)f2bf(2.f * ax) | ((uint)f2bf(2.f * ay) << 16);
        res.y = (uint)f2bf(2.f * az) | ((uint)f2bf(2.f * aw) << 16);
    } else {
        const uint2* prev = (const uint2*)((sign ? n_prev : p_prev) + q * QSZU);
        uint2 pu = prev[r * 8 + u];
        float rx = fmaf(1.875f, ax, -1.6875f * blo(pu.x));
        float ry = fmaf(1.875f, ay, -1.6875f * bhi(pu.x));
        float rz = fmaf(1.875f, az, -1.6875f * blo(pu.y));
        float rw = fmaf(1.875f, aw, -1.6875f * bhi(pu.y));
        res.x = (uint)f2bf(rx) | ((uint)f2bf(ry) << 16);
        res.y = (uint)f2bf(rz) | ((uint)f2bf(rw) << 16);
    }
    out[r * 8 + u] = res;
}

// ---------------- batch stats for pos & neg (quarter-blocked bf16 input) ----------------

__global__ __launch_bounds__(256) void stats2_k(const ushort* __restrict__ pos,
                                                const ushort* __restrict__ neg,
                                                float* __restrict__ sums,
                                                float* __restrict__ sumsq) {
    int b = blockIdx.x;            // 626 blocks
    int sign = b >= 313;
    int blk = b - sign * 313;
    const ushort* buf = sign ? neg : pos;
    int c = threadIdx.x & 127, half = threadIdx.x >> 7;
    int qq = c >> 5, cc = c & 31;
    const ushort* base = buf + (long)qq * QSZ16 + cc;
    int r0 = blk * 128;
    int rend = r0 + 128; if (rend > NNODES) rend = NNODES;
    float s = 0.f, s2 = 0.f;
    for (int r = r0 + half; r < rend; r += 2) {
        float v = bf2f(base[r * 32]);
        s += v;
        s2 = fmaf(v, v, s2);
    }
    __shared__ float sh[256], sh2[256];
    sh[threadIdx.x] = s; sh2[threadIdx.x] = s2;
    __syncthreads();
    if (threadIdx.x < 128) {
        int sb = 128 + sign * 128;
        atomicAdd(&sums[sb + c],  sh[c]  + sh[c + 128]);
        atomicAdd(&sumsq[sb + c], sh2[c] + sh2[c + 128]);
    }
}

__global__ void bnfin_k(const float* __restrict__ sum, const float* __restrict__ sumsq,
                        const float* __restrict__ g0, const float* __restrict__ be0,
                        const float* __restrict__ g1, const float* __restrict__ be1,
                        const float* __restrict__ g2, const float* __restrict__ be2,
                        float* __restrict__ bn) {
    int i = threadIdx.x;
    if (i >= 384) return;
    int s = i >> 7, c = i & 127;
    float mean = sum[i] * (1.f / NNODES);
    float var  = sumsq[i] * (1.f / NNODES) - mean * mean;
    const float* g = (s == 0) ? g0 : (s == 1) ? g1 : g2;
    const float* b = (s == 0) ? be0 : (s == 1) ? be1 : be2;
    float sc = g[c] * rsqrtf(var + 1e-5f);
    bn[s * 256 + c]       = sc;
    bn[s * 256 + 128 + c] = b[c] - mean * sc;
}

// ---------------- final MFMA GEMM K=384 with fused BN+PReLU+concat + row-norm ----------------

__global__ __launch_bounds__(256) void mfma_gemm_mlp_k(const ushort* __restrict__ org,
                                                       const ushort* __restrict__ pos,
                                                       const ushort* __restrict__ neg,
                                                       const float* __restrict__ bn,
                                                       const float* __restrict__ prelu_w,
                                                       const ushort* __restrict__ Bp,
                                                       float* __restrict__ Out) {
    int lane = threadIdx.x & 63, wave = threadIdx.x >> 6;
    long rbase = (long)blockIdx.x * 64 + wave * 16;
    int r = lane & 15, kg = lane >> 4;
    float pw = prelu_w[0];
    facc acc[8];
#pragma unroll
    for (int t = 0; t < 8; ++t) acc[t] = (facc){0.f, 0.f, 0.f, 0.f};
    const bfrag* Bq = (const bfrag*)Bp + lane;
#pragma unroll
    for (int ks = 0; ks < 12; ++ks) {
        int c = ks * 32 + kg * 8;          // concat column of first elem
        int s = c >> 7;
        int off = c & 127;
        const ushort* src = (s == 0) ? org : (s == 1) ? pos : neg;
        const uint* srcu = (const uint*)src;
        uint4 u = *(const uint4*)(srcu + (long)(off >> 5) * QSZU + (rbase + r) * 16 + ((off & 31) >> 1));
        float4 sc_lo = *(const float4*)(bn + s * 256 + off);
        float4 sc_hi = *(const float4*)(bn + s * 256 + off + 4);
        float4 sh_lo = *(const float4*)(bn + s * 256 + 128 + off);
        float4 sh_hi = *(const float4*)(bn + s * 256 + 128 + off + 4);
        uint uu[4] = {u.x, u.y, u.z, u.w};
        float scv[8] = {sc_lo.x, sc_lo.y, sc_lo.z, sc_lo.w, sc_hi.x, sc_hi.y, sc_hi.z, sc_hi.w};
        float shv[8] = {sh_lo.x, sh_lo.y, sh_lo.z, sh_lo.w, sh_hi.x, sh_hi.y, sh_hi.z, sh_hi.w};
        bfu av;
#pragma unroll
        for (int k = 0; k < 4; ++k) {
            float vx = __uint_as_float(uu[k] << 16);
            float vy = __uint_as_float(uu[k] & 0xFFFF0000u);
            float ox = fmaf(vx, scv[2 * k],     shv[2 * k]);     ox = (ox >= 0.f) ? ox : pw * ox;
            float oy = fmaf(vy, scv[2 * k + 1], shv[2 * k + 1]); oy = (oy >= 0.f) ? oy : pw * oy;
            av.u[k] = (uint)f2bf(ox) | ((uint)f2bf(oy) << 16);
        }
#pragma unroll
        for (int t = 0; t < 8; ++t)
            acc[t] = __builtin_amdgcn_mfma_f32_16x16x32_bf16(av.v, Bq[(ks * 8 + t) * 64], acc[t], 0, 0, 0);
    }
    long orow = rbase + kg * 4;
#pragma unroll
    for (int j = 0; j < 4; ++j) {
        float ss = 0.f;
#pragma unroll
        for (int t = 0; t < 8; ++t) ss = fmaf(acc[t][j], acc[t][j], ss);
        ss += __shfl_xor(ss, 1);
        ss += __shfl_xor(ss, 2);
        ss += __shfl_xor(ss, 4);
        ss += __shfl_xor(ss, 8);
        float inv = 1.f / fmaxf(sqrtf(ss), 1e-12f);
#pragma unroll
        for (int t = 0; t < 8; ++t)
            Out[(orow + j) * 128 + 16 * t + r] = acc[t][j] * inv;
    }
}

// ---------------- launch ----------------

extern "C" void kernel_launch(void* const* d_in, const int* in_sizes, int n_in,
                              void* d_out, int out_size, void* d_ws, size_t ws_size,
                              hipStream_t stream) {
    const float* x       = (const float*)d_in[0];
    const int*   pos_idx = (const int*)d_in[1];
    const float* pos_w   = (const float*)d_in[2];
    const int*   neg_idx = (const int*)d_in[3];
    const float* neg_w   = (const float*)d_in[4];
    const float* W_org   = (const float*)d_in[5];
    const float* W_pos   = (const float*)d_in[6];
    const float* W_neg   = (const float*)d_in[7];
    const float* g_org   = (const float*)d_in[8];
    const float* b_org   = (const float*)d_in[9];
    const float* g_pos   = (const float*)d_in[10];
    const float* b_pos   = (const float*)d_in[11];
    const float* g_neg   = (const float*)d_in[12];
    const float* b_neg   = (const float*)d_in[13];
    const float* prelu_w = (const float*)d_in[14];
    const float* W_mlp   = (const float*)d_in[15];
    float* out = (float*)d_out;

    char* ws = (char*)d_ws;
    const size_t FB = (size_t)NNODES * 128 * 2;        // 10,240,000 B per feature buffer
    ushort* org0b = (ushort*)(ws);
    ushort* p0b   = (ushort*)(ws + FB);
    ushort* n0b   = (ushort*)(ws + 2 * FB);
    int2* edges   = (int2*)(ws + 3 * FB);              // staging, 14,080,000 B
    uint* ecomp   = (uint*)(ws + 3 * FB + 14080000);   // compressed, 7,040,000 B
    char* small   = ws + 3 * FB + 14080000 + 7040000;
    int* ecnt     = (int*)small;                       // 5000 -> pad 5120
    float* sums   = (float*)(small + 5120);            // 1536
    float* sumsq  = (float*)(small + 5120 + 1536);     // 1536 (memset 0..8192)
    float* bn     = (float*)(small + 8192);            // 3072
    int2* rp2     = (int2*)(small + 8192 + 3072);      // 640,000
    ushort* Wb    = (ushort*)(small + 8192 + 3072 + 640000);   // 196,608 B
    uint* t1_pos  = (uint*)d_out;                      // blocked bf16 scratch halves of d_out
    uint* t1_neg  = (uint*)d_out + 4 * QSZU;

    hipMemsetAsync(small, 0, 8192, stream);

    partition_k<<<PBLKS, 256, 0, stream>>>(pos_idx, pos_w, neg_idx, neg_w, ecnt, edges);
    bucket_csr_k<<<2 * NBUCK, 256, 0, stream>>>(ecnt, edges, ecomp, rp2);
    pack_all_k<<<384, 256, 0, stream>>>(W_org, W_pos, W_neg, W_mlp, Wb);

    mfma_gemm3_k<<<625, 256, 0, stream>>>(x, Wb, Wb + 16384, Wb + 32768,
                                          org0b, p0b, n0b, sums, sumsq);

    // Jacobi (a=b=1, K=3): x1 = 2*A@x0 ; x2 = 1.875*A@x1 - 1.6875*x0
    spmmg_k<1><<<10000, 256, 0, stream>>>(rp2, ecomp,
        (const uint*)p0b, (const uint*)n0b, nullptr, nullptr, t1_pos, t1_neg);
    spmmg_k<2><<<10000, 256, 0, stream>>>(rp2, ecomp,
        t1_pos, t1_neg, (const uint*)p0b, (const uint*)n0b, (uint*)p0b, (uint*)n0b);

    stats2_k<<<626, 256, 0, stream>>>(p0b, n0b, sums, sumsq);
    bnfin_k<<<1, 384, 0, stream>>>(sums, sumsq, g_org, b_org, g_pos, b_pos, g_neg, b_neg, bn);
    mfma_gemm_mlp_k<<<625, 256, 0, stream>>>(org0b, p0b, n0b, bn, prelu_w, Wb + 49152, out);

    (void)in_sizes; (void)n_in; (void)out_size; (void)ws_size;
}